// Round 2
// baseline (730.926 us; speedup 1.0000x reference)
//
#include <hip/hip_runtime.h>
#include <cstddef>
#include <cstdint>

// Problem constants (from reference): B=4, N=512, F_IN=64, F_OUT=128
#define BB   4
#define NN   512
#define FIN  64
#define FOUT 128

// k_edges geometry: 256 blocks = B(4) x JHALF(2) x IPARTS(32), 512 threads.
#define IPARTS 32
#define IBLK   (NN / IPARTS)  // 16 i-rows per block
#define JH     (NN / 2)       // 256 j-columns per block
#define TE     512            // threads per k_edges block (8 waves)

typedef float f4 __attribute__((ext_vector_type(4)));

__device__ __forceinline__ float celu1(float x) {
  // jax.nn.celu with alpha=1: x>0 ? x : exp(x)-1
  return x > 0.0f ? x : expm1f(x);
}

// ---------------------------------------------------------------------------
// K1: pj[bn,f] = nodes[bn,:] . edge_W[f, 0:64]
//     pip[bn,f] = nodes[bn,:] . edge_W[f, 64:128] + edge_b[f]
// One block per (b,n) row, 128 threads (one per f).
// ---------------------------------------------------------------------------
__global__ __launch_bounds__(FOUT) void k_proj(
    const float* __restrict__ nodes, const float* __restrict__ eW,
    const float* __restrict__ eb, float* __restrict__ pj,
    float* __restrict__ pip) {
  const int bn = blockIdx.x;
  const int f  = threadIdx.x;
  __shared__ __align__(16) float x[FIN];
  if (f < FIN) x[f] = nodes[bn * FIN + f];
  __syncthreads();
  const float* w = eW + f * (2 * FIN);
  float aj = 0.f, ai = 0.f;
#pragma unroll
  for (int k = 0; k < FIN; k += 4) {
    f4 xv = *(const f4*)(x + k);
    f4 wj = *(const f4*)(w + k);
    f4 wi = *(const f4*)(w + FIN + k);
    aj += wj.x * xv.x + wj.y * xv.y + wj.z * xv.z + wj.w * xv.w;
    ai += wi.x * xv.x + wi.y * xv.y + wi.z * xv.z + wi.w * xv.w;
  }
  pj[bn * FOUT + f]  = aj;
  pip[bn * FOUT + f] = ai + eb[f];
}

// ---------------------------------------------------------------------------
// K2: edges[b,i,j,f] = (pj[b,j,f] + pip[b,i,f]) * sk[b,i,j]   (537 MB write)
//
// Structured like the 6.2 TB/s fillBuffer kernel: ONE barrier per block, then
// a pure store loop with no vmcnt waits and no syncthreads (hardware caps at
// 63 outstanding stores/wave = deep queue). 256 blocks (1/CU) x 512 threads.
// Block owns (b, j-half, 16 i-rows); per i-row it writes one sequential
// 128 KB run (16 sweeps x 8 KB, perfectly coalesced).
// pj fragment lives in 16 f4 REGISTERS per thread; sk/pip slabs in LDS (24 KB)
// read via lgkmcnt only.
// ---------------------------------------------------------------------------
__global__ __launch_bounds__(TE) void k_edges(
    const float* __restrict__ pj, const float* __restrict__ pip,
    const float* __restrict__ sk, float* __restrict__ edges) {
  const int xb  = blockIdx.x;       // [b(4)][jh(2)][ip(32)]
  const int ip  = xb & 31;
  const int jhf = (xb >> 5) & 1;
  const int b   = xb >> 6;
  const int tid = threadIdx.x;
  const int i0  = ip * IBLK;
  const int j0  = jhf * JH;

  __shared__ __align__(16) float lsk[IBLK][JH];    // 16 KB
  __shared__ __align__(16) float lpip[IBLK][FOUT]; //  8 KB

  const int jl = tid >> 5;        // 0..15: j-offset within a sweep
  const int f0 = (tid & 31) * 4;  // f4 column

  // pj fragment in registers: this thread's (j = s*16+jl, f0..f0+3) for s=0..15
  f4 pjr[16];
  {
    const float* src = pj + ((size_t)b * NN + j0) * FOUT;
#pragma unroll
    for (int s = 0; s < 16; ++s)
      pjr[s] = *(const f4*)(src + (s * 16 + jl) * FOUT + f0);
  }
  // stage pip slab [16 i][128 f] = 2048 floats (one f4 per thread)
  {
    const float* src = pip + ((size_t)b * NN + i0) * FOUT;
    *(f4*)(&lpip[0][0] + tid * 4) = *(const f4*)(src + tid * 4);
  }
  // stage sk slab [16 i][256 j] = 4096 floats (8 per thread, coalesced in j)
  {
#pragma unroll
    for (int r = 0; r < 8; ++r) {
      const int idx = r * TE + tid;  // 0..4095
      const int ii  = idx >> 8;
      const int jj  = idx & 255;
      lsk[ii][jj] = sk[((size_t)b * NN + i0 + ii) * NN + j0 + jj];
    }
  }
  __syncthreads();  // the ONLY barrier

  float* ep = edges + (((size_t)(b * NN + i0)) * NN + j0) * FOUT;
#pragma unroll 1
  for (int ii = 0; ii < IBLK; ++ii) {
    const f4 piv = *(const f4*)(&lpip[ii][f0]);
#pragma unroll
    for (int s = 0; s < 16; ++s) {
      const float sv = lsk[ii][s * 16 + jl];
      f4 v = (pjr[s] + piv) * sv;
      *(f4*)(ep + (size_t)s * (16 * FOUT) + tid * 4) = v;
    }
    ep += (size_t)NN * FOUT;
  }
}

// ---------------------------------------------------------------------------
// K3: out0[b,j,f] = mlp(nodes[b,j,:]) + r[b,j,:] . node_W[f,:] + node_b[f]
// where r[b,j,f] = sum_i (pj[b,j,f] + pip[b,i,f]) * sk[b,i,j]  (folded here;
// no nn_part workspace). One block per (b,j), 128 threads (one per f).
// Independent of k_edges' output. pip column reads are coalesced 512 B runs,
// L2-resident (pip = 1 MB).
// ---------------------------------------------------------------------------
__global__ __launch_bounds__(FOUT) void k_final(
    const float* __restrict__ nodes, const float* __restrict__ pj,
    const float* __restrict__ pip, const float* __restrict__ sk,
    const float* __restrict__ nW, const float* __restrict__ nb,
    const float* __restrict__ W0, const float* __restrict__ b0,
    const float* __restrict__ W1, const float* __restrict__ b1,
    const float* __restrict__ W2, const float* __restrict__ b2,
    float* __restrict__ out0) {
  const int bn = blockIdx.x;
  const int b  = bn >> 9;
  const int j  = bn & (NN - 1);
  const int f  = threadIdx.x;

  __shared__ __align__(16) float x[FIN];
  __shared__ __align__(16) float lsk[NN];  // sk column j (2 KB)
  __shared__ __align__(16) float rL[FOUT];
  __shared__ __align__(16) float hA[FOUT];
  __shared__ __align__(16) float hB[FOUT];

  if (f < FIN) x[f] = nodes[bn * FIN + f];
  // stage sk[:, j] (scattered 4B loads, L2/L3-resident: sk = 4 MB)
#pragma unroll
  for (int p = 0; p < 4; ++p)
    lsk[f + 128 * p] = sk[((size_t)b * NN + f + 128 * p) * NN + j];
  __syncthreads();

  // r[f] = sum_i (pj[b,j,f] + pip[b,i,f]) * sk[i]
  float r = 0.f;
  {
    const float pjv = pj[(b * NN + j) * FOUT + f];
    const float* pb = pip + (size_t)b * NN * FOUT + f;
#pragma unroll 8
    for (int i = 0; i < NN; ++i)
      r += (pjv + pb[(size_t)i * FOUT]) * lsk[i];
  }
  rL[f] = r;

  // h0 = celu(W0 @ x + b0)
  float s0 = b0[f];
  {
    const float* w = W0 + f * FIN;
#pragma unroll
    for (int k = 0; k < FIN; k += 4) {
      f4 wv = *(const f4*)(w + k);
      f4 xv = *(const f4*)(x + k);
      s0 += wv.x * xv.x + wv.y * xv.y + wv.z * xv.z + wv.w * xv.w;
    }
  }
  hA[f] = celu1(s0);
  __syncthreads();

  // h1 = celu(W1 @ h0 + b1); node linear on rL (independent of hA)
  float s1 = b1[f];
  {
    const float* w = W1 + f * FOUT;
#pragma unroll
    for (int k = 0; k < FOUT; k += 4) {
      f4 wv = *(const f4*)(w + k);
      f4 hv = *(const f4*)(hA + k);
      s1 += wv.x * hv.x + wv.y * hv.y + wv.z * hv.z + wv.w * hv.w;
    }
  }
  float nv = nb[f];
  {
    const float* w = nW + f * FOUT;
#pragma unroll
    for (int k = 0; k < FOUT; k += 4) {
      f4 wv = *(const f4*)(w + k);
      f4 rv = *(const f4*)(rL + k);
      nv += wv.x * rv.x + wv.y * rv.y + wv.z * rv.z + wv.w * rv.w;
    }
  }
  hB[f] = celu1(s1);
  __syncthreads();

  // h2 = W2 @ h1 + b2 ; out = h2 + node_linear
  float s2 = b2[f];
  {
    const float* w = W2 + f * FOUT;
#pragma unroll
    for (int k = 0; k < FOUT; k += 4) {
      f4 wv = *(const f4*)(w + k);
      f4 hv = *(const f4*)(hB + k);
      s2 += wv.x * hv.x + wv.y * hv.y + wv.z * hv.z + wv.w * hv.w;
    }
  }
  out0[bn * FOUT + f] = s2 + nv;
}

// ---------------------------------------------------------------------------
extern "C" void kernel_launch(void* const* d_in, const int* in_sizes, int n_in,
                              void* d_out, int out_size, void* d_ws,
                              size_t ws_size, hipStream_t stream) {
  const float* nodes    = (const float*)d_in[0];
  const float* skeleton = (const float*)d_in[1];
  const float* edge_W   = (const float*)d_in[2];
  const float* edge_b   = (const float*)d_in[3];
  const float* node_W   = (const float*)d_in[4];
  const float* node_b   = (const float*)d_in[5];
  const float* mlp_W0   = (const float*)d_in[6];
  const float* mlp_b0   = (const float*)d_in[7];
  const float* mlp_W1   = (const float*)d_in[8];
  const float* mlp_b1   = (const float*)d_in[9];
  const float* mlp_W2   = (const float*)d_in[10];
  const float* mlp_b2   = (const float*)d_in[11];

  float* out0  = (float*)d_out;                 // [B,N,FOUT]
  float* edges = out0 + (size_t)BB * NN * FOUT; // [B,N,N,FOUT]

  float* ws  = (float*)d_ws;
  float* pj  = ws;                          // [B*N,FOUT] 1 MB
  float* pip = ws + (size_t)BB * NN * FOUT; // [B*N,FOUT] 1 MB

  k_proj<<<BB * NN, FOUT, 0, stream>>>(nodes, edge_W, edge_b, pj, pip);
  k_edges<<<BB * 2 * IPARTS, TE, 0, stream>>>(pj, pip, skeleton, edges);
  k_final<<<BB * NN, FOUT, 0, stream>>>(nodes, pj, pip, skeleton, node_W,
                                        node_b, mlp_W0, mlp_b0, mlp_W1, mlp_b1,
                                        mlp_W2, mlp_b2, out0);
}